// Round 6
// baseline (321.475 us; speedup 1.0000x reference)
//
#include <hip/hip_runtime.h>
#include <math.h>

// Deepmd angular descriptor, f32 in / f32 out. B=8, N=4096, M=96, OUT_W=384.
//
// R21 = DECOMPOSITION ROUND (sacrificial). Four falsified theories so far
// (VGPR cap, in-flight bytes, convoy, bytes/instr); hard facts: every phase
// of this kernel moves data at ~3.35 TB/s (cold reads AND warm writes),
// additive read+compute (R17), invariant to occupancy 16-32 w/CU, VALU/LDS/
// width all non-binding. To locate the stall, kernel_launch issues FOUR
// dispatches, each = one template variant + a fixed ~45us s_memrealtime spin
// AFTER its work (dur = work + S; S cancels in differences; makes every
// dispatch clear the 41us fill visibility floor in rocprof top-5):
//   V3: spin only                         -> S (and wall-clock rate check)
//   V0: stream loads only, COLD, kept alive -> dur-S = isolated cold-read time
//       (~10us => loads fine alone, interaction problem;
//        ~18.6us => load path slow by itself)
//   V1: loads + LDS gather + geometry, warm -> gather/geom marginal
//   V2: full kernel, warm (writes output; last on stream) -> warm floor xcheck
// Consume machinery byte-identical to R15. Output written only by V2.
#define M_NB   96
#define OUT_W  384
#define NATOM  4096
#define WPB    8                    // 512 threads = 8 waves
#define ITERS  4                    // 2 rows per iteration -> 8 rows/wave
#define SPIN_TICKS 4500LL           // ~45 us at the typical 100 MHz realtime clk
#define LOWM   0x00000000FFFFFFFFull
#define HIGHM  0xFFFFFFFF00000000ull

#define KEEPI(x) asm volatile("" :: "v"(x))
#define KEEPF(x) asm volatile("" :: "v"(x))

__device__ __forceinline__ void spin_after_work(long long ticks) {
    const long long t1 = (long long)__builtin_amdgcn_s_memrealtime();
    while ((long long)__builtin_amdgcn_s_memrealtime() - t1 < ticks) {}
}

// fold one item (row floats [base,base+3)) into this lane's output slots:
// float4 owns [4*lane,4*lane+4), float2 owns [256+2*lane,256+2*lane+2)
__device__ __forceinline__ void merge3(float4& a4, float2& a2, int base,
                                       float v0, float v1, float v2, int lane)
{
    const int f4lo = 4 * lane;
    const int f2lo = 256 + 2 * lane;
    const float v[3] = {v0, v1, v2};
    #pragma unroll
    for (int t = 0; t < 3; ++t) {
        const int idx = base + t;
        if      (idx == f4lo)     a4.x = v[t];
        else if (idx == f4lo + 1) a4.y = v[t];
        else if (idx == f4lo + 2) a4.z = v[t];
        else if (idx == f4lo + 3) a4.w = v[t];
        else if (idx == f2lo)     a2.x = v[t];
        else if (idx == f2lo + 1) a2.y = v[t];
    }
}

template<int V>
__global__ __launch_bounds__(64 * WPB, 4) void deepmd_probe(
    const float* __restrict__ positions,  // [B,N,3]
    const float* __restrict__ cell,       // [B,3,3]
    const float* __restrict__ offsets,    // [B,N,M,3]
    const float* __restrict__ mask,       // [B,N,M]
    const int*   __restrict__ neighbors,  // [B,N,M]
    float*       __restrict__ out,        // [B,N,OUT_W]
    int N)
{
    __shared__ float4 pos4_s[NATOM];        // 64 KB padded position table

    const int tid  = threadIdx.x;
    const int wv   = tid >> 6;
    const int lane = tid & 63;

    const int p0 = blockIdx.x * (WPB * 2 * ITERS);   // 64 rows per block
    const int b  = p0 / N;                           // uniform (64 | N)

    // ---- stage batch positions -> LDS (all variants, incl. V3 baseline) ----
    {
        const float* pb_ = positions + (size_t)b * N * 3;
        for (int a = tid; a < NATOM; a += 64 * WPB) {
            const float3 v = *(const float3*)(pb_ + 3 * a);
            pos4_s[a] = make_float4(v.x, v.y, v.z, 0.f);
        }
    }
    __syncthreads();

    if (V != 3) {
        const float* cb = cell + (size_t)b * 9;      // uniform scalar loads
        const float c00 = cb[0], c01 = cb[1], c02 = cb[2];
        const float c10 = cb[3], c11 = cb[4], c12 = cb[5];
        const float c20 = cb[6], c21 = cb[7], c22 = cb[8];

        const int r0 = p0 + wv * (2 * ITERS);        // wave's first row

        #pragma unroll
        for (int it = 0; it < ITERS; ++it) {
            const int  q0   = r0 + it * 2;
            const long base = (long)q0 * M_NB;       // contiguous 192 elements
            const long e0 = base + lane, e1 = e0 + 64, e2 = e0 + 128;

            // ---- stream loads (R15 shape: 9 VMEM/iter) ----
            const int   j0 = neighbors[e0], j1 = neighbors[e1], j2 = neighbors[e2];
            const float m0 = mask[e0],      m1 = mask[e1],      m2 = mask[e2];
            const float3 o0 = *(const float3*)(offsets + e0 * 3);
            const float3 o1 = *(const float3*)(offsets + e1 * 3);
            const float3 o2 = *(const float3*)(offsets + e2 * 3);

            if (V == 0) {       // loads only: keep everything live, no use
                KEEPI(j0); KEEPI(j1); KEEPI(j2);
                KEEPF(m0); KEEPF(m1); KEEPF(m2);
                KEEPF(o0.x); KEEPF(o0.y); KEEPF(o0.z);
                KEEPF(o1.x); KEEPF(o1.y); KEEPF(o1.z);
                KEEPF(o2.x); KEEPF(o2.y); KEEPF(o2.z);
                continue;
            }

            // ---- LDS gathers ----
            const int nn0 = q0 - b * N;
            const float4 pi0 = pos4_s[nn0];          // uniform broadcasts
            const float4 pi1 = pos4_s[nn0 + 1];
            const float4 pj0 = pos4_s[j0];
            const float4 pj1 = pos4_s[j1];
            const float4 pj2 = pos4_s[j2];
            const float4 pa  = (lane < 32) ? pi0 : pi1;

            // ---- cut per item (w = cut * dis_vec stored in-place) ----
            float w0x = pj0.x - pi0.x + o0.x * c00 + o0.y * c10 + o0.z * c20;
            float w0y = pj0.y - pi0.y + o0.x * c01 + o0.y * c11 + o0.z * c21;
            float w0z = pj0.z - pi0.z + o0.x * c02 + o0.y * c12 + o0.z * c22;
            float d   = sqrtf(w0x * w0x + w0y * w0y + w0z * w0z + 1e-12f);
            float c0v = 0.f;
            if (m0 != 0.f && d < 6.f)
                c0v = 0.5f * (__cosf(d * 0.52359877559829887f) + 1.f) / d;
            w0x *= c0v; w0y *= c0v; w0z *= c0v;

            float w1x = pj1.x - pa.x + o1.x * c00 + o1.y * c10 + o1.z * c20;
            float w1y = pj1.y - pa.y + o1.x * c01 + o1.y * c11 + o1.z * c21;
            float w1z = pj1.z - pa.z + o1.x * c02 + o1.y * c12 + o1.z * c22;
            d = sqrtf(w1x * w1x + w1y * w1y + w1z * w1z + 1e-12f);
            float c1v = 0.f;
            if (m1 != 0.f && d < 6.f)
                c1v = 0.5f * (__cosf(d * 0.52359877559829887f) + 1.f) / d;
            w1x *= c1v; w1y *= c1v; w1z *= c1v;

            float w2x = pj2.x - pi1.x + o2.x * c00 + o2.y * c10 + o2.z * c20;
            float w2y = pj2.y - pi1.y + o2.x * c01 + o2.y * c11 + o2.z * c21;
            float w2z = pj2.z - pi1.z + o2.x * c02 + o2.y * c12 + o2.z * c22;
            d = sqrtf(w2x * w2x + w2y * w2y + w2z * w2z + 1e-12f);
            float c2v = 0.f;
            if (m2 != 0.f && d < 6.f)
                c2v = 0.5f * (__cosf(d * 0.52359877559829887f) + 1.f) / d;
            w2x *= c2v; w2y *= c2v; w2z *= c2v;

            if (V == 1) {       // loads+gather+geometry: keep results, stop
                KEEPF(w0x); KEEPF(w0y); KEEPF(w0z); KEEPF(c0v);
                KEEPF(w1x); KEEPF(w1y); KEEPF(w1z); KEEPF(c1v);
                KEEPF(w2x); KEEPF(w2y); KEEPF(w2z); KEEPF(c2v);
                continue;
            }

            // ---- row0: rank + register merge ----
            float4 a4 = make_float4(0.f, 0.f, 0.f, 0.f);
            float2 a2 = make_float2(0.f, 0.f);
            unsigned long long t = __ballot(c0v != 0.f);
            while (t) {                              // item m = s (c0 owner)
                const int s = (int)__builtin_ctzll(t); t &= t - 1;
                const float c = __shfl(c0v, s);
                const int rank = __popcll(__ballot(c0v > c))
                               + __popcll(__ballot(c1v > c) & LOWM)
                               + __popcll(__ballot(c0v == c) & ((1ull << s) - 1ull));
                merge3(a4, a2, 3 * rank,
                       __shfl(w0x, s), __shfl(w0y, s), __shfl(w0z, s), lane);
            }
            t = __ballot(c1v != 0.f) & LOWM;
            while (t) {                              // item m = 64+s (c1 low)
                const int s = (int)__builtin_ctzll(t); t &= t - 1;
                const float c = __shfl(c1v, s);
                const int rank = __popcll(__ballot(c0v > c))
                               + __popcll(__ballot(c1v > c) & LOWM)
                               + __popcll(__ballot(c0v == c))
                               + __popcll(__ballot(c1v == c) & LOWM & ((1ull << s) - 1ull));
                merge3(a4, a2, 3 * rank,
                       __shfl(w1x, s), __shfl(w1y, s), __shfl(w1z, s), lane);
            }
            float* row0 = out + (size_t)q0 * OUT_W;
            ((float4*)row0)[lane] = a4;
            ((float2*)(row0 + 256))[lane] = a2;

            // ---- row1: rank + register merge ----
            float4 b4 = make_float4(0.f, 0.f, 0.f, 0.f);
            float2 b2 = make_float2(0.f, 0.f);
            t = __ballot(c1v != 0.f) & HIGHM;
            while (t) {                              // item m = s-32 (c1 high)
                const int s = (int)__builtin_ctzll(t); t &= t - 1;
                const float c = __shfl(c1v, s);
                const int rank = __popcll(__ballot(c1v > c) & HIGHM)
                               + __popcll(__ballot(c2v > c))
                               + __popcll(__ballot(c1v == c) & HIGHM & ((1ull << s) - 1ull));
                merge3(b4, b2, 3 * rank,
                       __shfl(w1x, s), __shfl(w1y, s), __shfl(w1z, s), lane);
            }
            t = __ballot(c2v != 0.f);
            while (t) {                              // item m = 32+s (c2 owner)
                const int s = (int)__builtin_ctzll(t); t &= t - 1;
                const float c = __shfl(c2v, s);
                const int rank = __popcll(__ballot(c1v > c) & HIGHM)
                               + __popcll(__ballot(c2v > c))
                               + __popcll(__ballot(c1v == c) & HIGHM)
                               + __popcll(__ballot(c2v == c) & ((1ull << s) - 1ull));
                merge3(b4, b2, 3 * rank,
                       __shfl(w2x, s), __shfl(w2y, s), __shfl(w2z, s), lane);
            }
            float* row1 = out + (size_t)(q0 + 1) * OUT_W;
            ((float4*)row1)[lane] = b4;
            ((float2*)(row1 + 256))[lane] = b2;
        }
    }

    // ---- additive spin pad: dur = work + S, S cancels in differences ----
    spin_after_work(SPIN_TICKS);
}

extern "C" void kernel_launch(void* const* d_in, const int* in_sizes, int n_in,
                              void* d_out, int out_size, void* d_ws, size_t ws_size,
                              hipStream_t stream) {
    const float* positions = (const float*)d_in[0];
    const float* cell      = (const float*)d_in[1];
    const float* offsets   = (const float*)d_in[2];
    const float* mask      = (const float*)d_in[3];
    const int*   neighbors = (const int*)d_in[4];
    float*       out       = (float*)d_out;

    const int BN = in_sizes[0] / 3;        // B*N = 32768
    const int B  = in_sizes[1] / 9;        // 8
    const int N  = BN / B;                 // 4096

    dim3 block(64 * WPB, 1, 1);                // 512 threads = 8 waves
    dim3 grid(BN / (WPB * 2 * ITERS), 1, 1);   // 512 blocks

    // order matters: V3 touches ~nothing (spin baseline), V0 sees COLD
    // streams, V1/V2 run warm; V2 (full) writes the output, last on stream.
    deepmd_probe<3><<<grid, block, 0, stream>>>(positions, cell, offsets, mask, neighbors, out, N);
    deepmd_probe<0><<<grid, block, 0, stream>>>(positions, cell, offsets, mask, neighbors, out, N);
    deepmd_probe<1><<<grid, block, 0, stream>>>(positions, cell, offsets, mask, neighbors, out, N);
    deepmd_probe<2><<<grid, block, 0, stream>>>(positions, cell, offsets, mask, neighbors, out, N);
}

// Round 7
// 123.225 us; speedup vs baseline: 2.6089x; 2.6089x over previous
//
#include <hip/hip_runtime.h>
#include <math.h>

// Deepmd angular descriptor, f32 in / f32 out. B=8, N=4096, M=96, OUT_W=384.
//
// R22: non-temporal streams + full-depth prefetch.
// R21 decomposition (spin-padded variants): cold loads ALONE = 23 us
// (63 MB @ 2.7 TB/s), ballot/merge/store = 11 us VALU-serial, additive.
// Theory: the harness's 268 MB poison fill leaves L3 fully DIRTY; every
// read miss evicts a dirty line -> writeback, stores add eviction + RFO
// (the 15 MB warm FETCH). Actual HBM traffic ~2x visible -> pipe already
// saturated at ~6 TB/s; "3.3 TB/s" is the visible half. Tax is per-miss,
// which is why occupancy/width/prefetch/barriers never moved it.
// Fix: __builtin_nontemporal_load on ALL stream loads (never re-read),
// __builtin_nontemporal_store on output (never read) -> no L3 allocation,
// no dirty evictions, no RFO. Plus full 4-deep prefetch: all 36 stream
// loads issued before any consume (~97 VGPR < 128 cap) so compute of
// iter k overlaps loads of iters k+1..3.
// Shell = R16: 512 thr, 64 KB float4 pos LDS (cached loads - reused 96x),
// one __syncthreads, grid 512, 2 blocks/CU, 16 w/CU.
// Consume machinery (ballot-rank + register merge) byte-identical to R15.
#define M_NB   96
#define OUT_W  384
#define NATOM  4096
#define WPB    8                    // 512 threads = 8 waves
#define ITERS  4                    // 2 rows per iteration -> 8 rows/wave
#define LOWM   0x00000000FFFFFFFFull
#define HIGHM  0xFFFFFFFF00000000ull

typedef float f32x4_t __attribute__((ext_vector_type(4)));
typedef float f32x2_t __attribute__((ext_vector_type(2)));

__device__ __forceinline__ float ntldf(const float* p) {
    return __builtin_nontemporal_load(p);
}
__device__ __forceinline__ int ntldi(const int* p) {
    return __builtin_nontemporal_load(p);
}

struct Pref {
    int    j0, j1, j2;
    float  m0, m1, m2;
    float3 o0, o1, o2;
};

__device__ __forceinline__ void ntpref(Pref& P,
                                       const int* __restrict__ nbr,
                                       const float* __restrict__ msk,
                                       const float* __restrict__ offs,
                                       long e0)
{
    const long e1 = e0 + 64, e2 = e0 + 128;
    P.j0 = ntldi(nbr + e0); P.j1 = ntldi(nbr + e1); P.j2 = ntldi(nbr + e2);
    P.m0 = ntldf(msk + e0); P.m1 = ntldf(msk + e1); P.m2 = ntldf(msk + e2);
    P.o0 = make_float3(ntldf(offs + 3*e0), ntldf(offs + 3*e0 + 1), ntldf(offs + 3*e0 + 2));
    P.o1 = make_float3(ntldf(offs + 3*e1), ntldf(offs + 3*e1 + 1), ntldf(offs + 3*e1 + 2));
    P.o2 = make_float3(ntldf(offs + 3*e2), ntldf(offs + 3*e2 + 1), ntldf(offs + 3*e2 + 2));
}

// fold one item (row floats [base,base+3)) into this lane's output slots:
// float4 owns [4*lane,4*lane+4), float2 owns [256+2*lane,256+2*lane+2)
__device__ __forceinline__ void merge3(float4& a4, float2& a2, int base,
                                       float v0, float v1, float v2, int lane)
{
    const int f4lo = 4 * lane;
    const int f2lo = 256 + 2 * lane;
    const float v[3] = {v0, v1, v2};
    #pragma unroll
    for (int t = 0; t < 3; ++t) {
        const int idx = base + t;
        if      (idx == f4lo)     a4.x = v[t];
        else if (idx == f4lo + 1) a4.y = v[t];
        else if (idx == f4lo + 2) a4.z = v[t];
        else if (idx == f4lo + 3) a4.w = v[t];
        else if (idx == f2lo)     a2.x = v[t];
        else if (idx == f2lo + 1) a2.y = v[t];
    }
}

// consume one pair (rows q0, q0+1) from prefetched stream regs.
__device__ __forceinline__ void consume_pair(
    const Pref& P, int q0, int nbase, const float4* pos4_s,
    float* __restrict__ out,
    float c00, float c01, float c02, float c10, float c11, float c12,
    float c20, float c21, float c22, int lane)
{
    const int nn0 = q0 - nbase;
    const float4 pi0 = pos4_s[nn0];          // uniform broadcasts
    const float4 pi1 = pos4_s[nn0 + 1];
    const float4 pj0 = pos4_s[P.j0];
    const float4 pj1 = pos4_s[P.j1];
    const float4 pj2 = pos4_s[P.j2];
    const float4 pa  = (lane < 32) ? pi0 : pi1;   // item1's own atom

    // ---- cut per item (w = cut * dis_vec stored in-place) ----
    float w0x = pj0.x - pi0.x + P.o0.x * c00 + P.o0.y * c10 + P.o0.z * c20;
    float w0y = pj0.y - pi0.y + P.o0.x * c01 + P.o0.y * c11 + P.o0.z * c21;
    float w0z = pj0.z - pi0.z + P.o0.x * c02 + P.o0.y * c12 + P.o0.z * c22;
    float d   = sqrtf(w0x * w0x + w0y * w0y + w0z * w0z + 1e-12f);
    float c0v = 0.f;
    if (P.m0 != 0.f && d < 6.f)
        c0v = 0.5f * (__cosf(d * 0.52359877559829887f) + 1.f) / d;
    w0x *= c0v; w0y *= c0v; w0z *= c0v;

    float w1x = pj1.x - pa.x + P.o1.x * c00 + P.o1.y * c10 + P.o1.z * c20;
    float w1y = pj1.y - pa.y + P.o1.x * c01 + P.o1.y * c11 + P.o1.z * c21;
    float w1z = pj1.z - pa.z + P.o1.x * c02 + P.o1.y * c12 + P.o1.z * c22;
    d = sqrtf(w1x * w1x + w1y * w1y + w1z * w1z + 1e-12f);
    float c1v = 0.f;
    if (P.m1 != 0.f && d < 6.f)
        c1v = 0.5f * (__cosf(d * 0.52359877559829887f) + 1.f) / d;
    w1x *= c1v; w1y *= c1v; w1z *= c1v;

    float w2x = pj2.x - pi1.x + P.o2.x * c00 + P.o2.y * c10 + P.o2.z * c20;
    float w2y = pj2.y - pi1.y + P.o2.x * c01 + P.o2.y * c11 + P.o2.z * c21;
    float w2z = pj2.z - pi1.z + P.o2.x * c02 + P.o2.y * c12 + P.o2.z * c22;
    d = sqrtf(w2x * w2x + w2y * w2y + w2z * w2z + 1e-12f);
    float c2v = 0.f;
    if (P.m2 != 0.f && d < 6.f)
        c2v = 0.5f * (__cosf(d * 0.52359877559829887f) + 1.f) / d;
    w2x *= c2v; w2y *= c2v; w2z *= c2v;

    // ---- row0: rank + register merge ----
    // rank(m) = #{k: cut_k > cut_m} + #{k<m: cut_k == cut_m}
    float4 a4 = make_float4(0.f, 0.f, 0.f, 0.f);
    float2 a2 = make_float2(0.f, 0.f);
    unsigned long long t = __ballot(c0v != 0.f);
    while (t) {                                  // item m = s (c0 owner)
        const int s = (int)__builtin_ctzll(t); t &= t - 1;
        const float c = __shfl(c0v, s);
        const int rank = __popcll(__ballot(c0v > c))
                       + __popcll(__ballot(c1v > c) & LOWM)
                       + __popcll(__ballot(c0v == c) & ((1ull << s) - 1ull));
        merge3(a4, a2, 3 * rank,
               __shfl(w0x, s), __shfl(w0y, s), __shfl(w0z, s), lane);
    }
    t = __ballot(c1v != 0.f) & LOWM;
    while (t) {                                  // item m = 64+s (c1 low)
        const int s = (int)__builtin_ctzll(t); t &= t - 1;
        const float c = __shfl(c1v, s);
        const int rank = __popcll(__ballot(c0v > c))
                       + __popcll(__ballot(c1v > c) & LOWM)
                       + __popcll(__ballot(c0v == c))
                       + __popcll(__ballot(c1v == c) & LOWM & ((1ull << s) - 1ull));
        merge3(a4, a2, 3 * rank,
               __shfl(w1x, s), __shfl(w1y, s), __shfl(w1z, s), lane);
    }
    float* row0 = out + (size_t)q0 * OUT_W;
    {
        f32x4_t av; av.x = a4.x; av.y = a4.y; av.z = a4.z; av.w = a4.w;
        __builtin_nontemporal_store(av, (f32x4_t*)row0 + lane);
        f32x2_t a2v; a2v.x = a2.x; a2v.y = a2.y;
        __builtin_nontemporal_store(a2v, (f32x2_t*)(row0 + 256) + lane);
    }

    // ---- row1: rank + register merge ----
    float4 b4 = make_float4(0.f, 0.f, 0.f, 0.f);
    float2 b2 = make_float2(0.f, 0.f);
    t = __ballot(c1v != 0.f) & HIGHM;
    while (t) {                                  // item m = s-32 (c1 high)
        const int s = (int)__builtin_ctzll(t); t &= t - 1;
        const float c = __shfl(c1v, s);
        const int rank = __popcll(__ballot(c1v > c) & HIGHM)
                       + __popcll(__ballot(c2v > c))
                       + __popcll(__ballot(c1v == c) & HIGHM & ((1ull << s) - 1ull));
        merge3(b4, b2, 3 * rank,
               __shfl(w1x, s), __shfl(w1y, s), __shfl(w1z, s), lane);
    }
    t = __ballot(c2v != 0.f);
    while (t) {                                  // item m = 32+s (c2 owner)
        const int s = (int)__builtin_ctzll(t); t &= t - 1;
        const float c = __shfl(c2v, s);
        const int rank = __popcll(__ballot(c1v > c) & HIGHM)
                       + __popcll(__ballot(c2v > c))
                       + __popcll(__ballot(c1v == c) & HIGHM)
                       + __popcll(__ballot(c2v == c) & ((1ull << s) - 1ull));
        merge3(b4, b2, 3 * rank,
               __shfl(w2x, s), __shfl(w2y, s), __shfl(w2z, s), lane);
    }
    float* row1 = out + (size_t)(q0 + 1) * OUT_W;
    {
        f32x4_t bv; bv.x = b4.x; bv.y = b4.y; bv.z = b4.z; bv.w = b4.w;
        __builtin_nontemporal_store(bv, (f32x4_t*)row1 + lane);
        f32x2_t b2v; b2v.x = b2.x; b2v.y = b2.y;
        __builtin_nontemporal_store(b2v, (f32x2_t*)(row1 + 256) + lane);
    }
}

__global__ __launch_bounds__(64 * WPB, 4) void deepmd_angular_kernel(
    const float* __restrict__ positions,  // [B,N,3]
    const float* __restrict__ cell,       // [B,3,3]
    const float* __restrict__ offsets,    // [B,N,M,3]
    const float* __restrict__ mask,       // [B,N,M]
    const int*   __restrict__ neighbors,  // [B,N,M]
    float*       __restrict__ out,        // [B,N,OUT_W]
    int N)
{
    __shared__ float4 pos4_s[NATOM];        // 64 KB padded position table

    const int tid  = threadIdx.x;
    const int wv   = tid >> 6;
    const int lane = tid & 63;

    const int p0 = blockIdx.x * (WPB * 2 * ITERS);   // 64 rows per block
    const int b  = p0 / N;                           // uniform (64 | N)

    // ---- stage batch positions -> LDS (cached loads: reused 96x) ----
    {
        const float* pb_ = positions + (size_t)b * N * 3;
        for (int a = tid; a < NATOM; a += 64 * WPB) {
            const float3 v = *(const float3*)(pb_ + 3 * a);
            pos4_s[a] = make_float4(v.x, v.y, v.z, 0.f);
        }
    }
    __syncthreads();                             // only barrier in the kernel

    const float* cb = cell + (size_t)b * 9;      // uniform -> scalar loads
    const float c00 = cb[0], c01 = cb[1], c02 = cb[2];
    const float c10 = cb[3], c11 = cb[4], c12 = cb[5];
    const float c20 = cb[6], c21 = cb[7], c22 = cb[8];

    const int  r0    = p0 + wv * (2 * ITERS);    // wave's first row
    const long base0 = (long)r0 * M_NB;          // contiguous 768 elements
    const int  nbase = b * N;

    // ---- full-depth prefetch: all 36 stream loads in flight ----
    Pref P0, P1, P2, P3;
    ntpref(P0, neighbors, mask, offsets, base0 + 0L * 192 + lane);
    ntpref(P1, neighbors, mask, offsets, base0 + 1L * 192 + lane);
    ntpref(P2, neighbors, mask, offsets, base0 + 2L * 192 + lane);
    ntpref(P3, neighbors, mask, offsets, base0 + 3L * 192 + lane);

    consume_pair(P0, r0 + 0, nbase, pos4_s, out,
                 c00, c01, c02, c10, c11, c12, c20, c21, c22, lane);
    consume_pair(P1, r0 + 2, nbase, pos4_s, out,
                 c00, c01, c02, c10, c11, c12, c20, c21, c22, lane);
    consume_pair(P2, r0 + 4, nbase, pos4_s, out,
                 c00, c01, c02, c10, c11, c12, c20, c21, c22, lane);
    consume_pair(P3, r0 + 6, nbase, pos4_s, out,
                 c00, c01, c02, c10, c11, c12, c20, c21, c22, lane);
}

extern "C" void kernel_launch(void* const* d_in, const int* in_sizes, int n_in,
                              void* d_out, int out_size, void* d_ws, size_t ws_size,
                              hipStream_t stream) {
    const float* positions = (const float*)d_in[0];
    const float* cell      = (const float*)d_in[1];
    const float* offsets   = (const float*)d_in[2];
    const float* mask      = (const float*)d_in[3];
    const int*   neighbors = (const int*)d_in[4];
    float*       out       = (float*)d_out;

    const int BN = in_sizes[0] / 3;        // B*N = 32768
    const int B  = in_sizes[1] / 9;        // 8
    const int N  = BN / B;                 // 4096

    dim3 block(64 * WPB, 1, 1);                // 512 threads = 8 waves
    dim3 grid(BN / (WPB * 2 * ITERS), 1, 1);   // 512 blocks = 2/CU resident
    deepmd_angular_kernel<<<grid, block, 0, stream>>>(
        positions, cell, offsets, mask, neighbors, out, N);
}

// Round 8
// 121.985 us; speedup vs baseline: 2.6354x; 1.0102x over previous
//
#include <hip/hip_runtime.h>
#include <math.h>

// Deepmd angular descriptor, f32 in / f32 out. B=8, N=4096, M=96, OUT_W=384.
//
// R23 = R20 (proven-correct fat-load shell, 34us) + NON-TEMPORAL bits on
// exactly the accesses that are full-line and never line-shared:
//   * neighbors+mask fat loads (int4/float4, lanes<48, 768B/instr) -> nt
//   * output stores (b128 + b64, full row coverage, never re-read) -> nt
//   * offsets stay CACHED dwordx3 (their lines are shared across lanes
//     within/between instrs; nt-ing them was R22's ~x3-traffic bug)
//   * positions stay cached (reused 96x via LDS staging; 384KB total)
// Theory being tested (last lever before roofline declaration): harness
// poison fill leaves 256MB L3 100% dirty -> cold kernel pays dirty-victim
// writeback on every read miss AND store allocation: 63+63+50+50 = 226 MB
// @ 6.6 TB/s = 34.2 us = observed kernel time exactly. nt (if it bypasses
// MALL allocation on gfx950) removes ~75 MB of that tax -> ~24-27 us.
// Shell identical to R20: 512 thr, 64KB float4 pos LDS, one __syncthreads,
// grid 512, 2 blocks/CU, 16 w/CU. Ballot-rank + register merge byte-equal.
#define M_NB   96
#define OUT_W  384
#define NATOM  4096
#define WPB    8                    // waves per block (512 threads)
#define ITERS  4                    // 2 rows per iteration -> 8 rows/wave
#define LOWM   0x00000000FFFFFFFFull
#define HIGHM  0xFFFFFFFF00000000ull

typedef int   i32x4_t __attribute__((ext_vector_type(4)));
typedef float f32x4_t __attribute__((ext_vector_type(4)));
typedef float f32x2_t __attribute__((ext_vector_type(2)));

// fold one item (row floats [base,base+3)) into this lane's output slots:
// float4 owns [4*lane,4*lane+4), float2 owns [256+2*lane,256+2*lane+2)
__device__ __forceinline__ void merge3(float4& a4, float2& a2, int base,
                                       float v0, float v1, float v2, int lane)
{
    const int f4lo = 4 * lane;
    const int f2lo = 256 + 2 * lane;
    const float v[3] = {v0, v1, v2};
    #pragma unroll
    for (int t = 0; t < 3; ++t) {
        const int idx = base + t;
        if      (idx == f4lo)     a4.x = v[t];
        else if (idx == f4lo + 1) a4.y = v[t];
        else if (idx == f4lo + 2) a4.z = v[t];
        else if (idx == f4lo + 3) a4.w = v[t];
        else if (idx == f2lo)     a2.x = v[t];
        else if (idx == f2lo + 1) a2.y = v[t];
    }
}

__global__ __launch_bounds__(64 * WPB, 4) void deepmd_angular_kernel(
    const float* __restrict__ positions,  // [B,N,3]
    const float* __restrict__ cell,       // [B,3,3]
    const float* __restrict__ offsets,    // [B,N,M,3]
    const float* __restrict__ mask,       // [B,N,M]
    const int*   __restrict__ neighbors,  // [B,N,M]
    float*       __restrict__ out,        // [B,N,OUT_W]
    int N)
{
    __shared__ float4 pos4_s[NATOM];        // 64 KB padded position table

    const int tid  = threadIdx.x;
    const int wv   = tid >> 6;
    const int lane = tid & 63;

    const int p0 = blockIdx.x * (WPB * 2 * ITERS);   // 64 rows per block
    const int b  = p0 / N;                           // uniform (64 | N)

    // ---- stage batch positions -> LDS (padded to 16 B/atom; cached) ----
    {
        const float* pb_ = positions + (size_t)b * N * 3;
        for (int a = tid; a < NATOM; a += 64 * WPB) {
            const float3 v = *(const float3*)(pb_ + 3 * a);
            pos4_s[a] = make_float4(v.x, v.y, v.z, 0.f);
        }
    }
    __syncthreads();                             // only barrier in the kernel

    const float* cb = cell + (size_t)b * 9;      // uniform -> scalar loads
    const float c00 = cb[0], c01 = cb[1], c02 = cb[2];
    const float c10 = cb[3], c11 = cb[4], c12 = cb[5];
    const float c20 = cb[6], c21 = cb[7], c22 = cb[8];

    const int r0 = p0 + wv * (2 * ITERS);        // wave's first row
    const int lq = lane >> 2;                    // fat-load source sublane
    const int lc = lane & 3;                     // fat-load component select

    #pragma unroll
    for (int it = 0; it < ITERS; ++it) {
        const int  q0   = r0 + it * 2;           // first of this iter's 2 rows
        const long base = (long)q0 * M_NB;       // contiguous 192 elements

        // ---- fat stream loads, NON-TEMPORAL: 768 B/instr, full lines,
        // no cross-instruction line sharing -> bypass-safe ----
        i32x4_t nv = {0, 0, 0, 0};
        f32x4_t mv = {0.f, 0.f, 0.f, 0.f};
        if (lane < 48) {                         // 192 elems = 48 int4/float4
            nv = __builtin_nontemporal_load((const i32x4_t*)(neighbors + base) + lane);
            mv = __builtin_nontemporal_load((const f32x4_t*)(mask      + base) + lane);
        }
        // offsets: cached dwordx3 (lines shared across lanes; nt unsafe here)
        const float3 o0 = *(const float3*)(offsets + (base + lane) * 3);
        const float3 o1 = *(const float3*)(offsets + (base + lane + 64) * 3);
        const float3 o2 = *(const float3*)(offsets + (base + lane + 128) * 3);

        // ---- redistribute to R15 layout: slot s of lane l = component
        // (l&3) of fat-load lane 16*s+(l>>2) ----
        int   j0, j1, j2;
        float m0, m1, m2;
        #pragma unroll
        for (int s = 0; s < 3; ++s) {
            const int src = 16 * s + lq;
            const int   ax = __shfl(nv.x, src), ay = __shfl(nv.y, src);
            const int   az = __shfl(nv.z, src), aw = __shfl(nv.w, src);
            const int   jl = (lc & 1) ? ay : ax;
            const int   jh = (lc & 1) ? aw : az;
            const int   jj = (lc & 2) ? jh : jl;
            const float bx = __shfl(mv.x, src), by = __shfl(mv.y, src);
            const float bz = __shfl(mv.z, src), bw = __shfl(mv.w, src);
            const float ml = (lc & 1) ? by : bx;
            const float mh = (lc & 1) ? bw : bz;
            const float mm = (lc & 2) ? mh : ml;
            if (s == 0) { j0 = jj; m0 = mm; }
            else if (s == 1) { j1 = jj; m1 = mm; }
            else { j2 = jj; m2 = mm; }
        }

        // ---- LDS gathers ----
        const int nn0 = q0 - b * N;
        const float4 pi0 = pos4_s[nn0];          // uniform broadcasts
        const float4 pi1 = pos4_s[nn0 + 1];
        const float4 pj0 = pos4_s[j0];
        const float4 pj1 = pos4_s[j1];
        const float4 pj2 = pos4_s[j2];
        const float4 pa  = (lane < 32) ? pi0 : pi1;   // item1's own atom

        // ---- cut per item (w = cut * dis_vec stored in-place) ----
        float w0x = pj0.x - pi0.x + o0.x * c00 + o0.y * c10 + o0.z * c20;
        float w0y = pj0.y - pi0.y + o0.x * c01 + o0.y * c11 + o0.z * c21;
        float w0z = pj0.z - pi0.z + o0.x * c02 + o0.y * c12 + o0.z * c22;
        float d   = sqrtf(w0x * w0x + w0y * w0y + w0z * w0z + 1e-12f);
        float c0v = 0.f;
        if (m0 != 0.f && d < 6.f)
            c0v = 0.5f * (__cosf(d * 0.52359877559829887f) + 1.f) / d;
        w0x *= c0v; w0y *= c0v; w0z *= c0v;

        float w1x = pj1.x - pa.x + o1.x * c00 + o1.y * c10 + o1.z * c20;
        float w1y = pj1.y - pa.y + o1.x * c01 + o1.y * c11 + o1.z * c21;
        float w1z = pj1.z - pa.z + o1.x * c02 + o1.y * c12 + o1.z * c22;
        d = sqrtf(w1x * w1x + w1y * w1y + w1z * w1z + 1e-12f);
        float c1v = 0.f;
        if (m1 != 0.f && d < 6.f)
            c1v = 0.5f * (__cosf(d * 0.52359877559829887f) + 1.f) / d;
        w1x *= c1v; w1y *= c1v; w1z *= c1v;

        float w2x = pj2.x - pi1.x + o2.x * c00 + o2.y * c10 + o2.z * c20;
        float w2y = pj2.y - pi1.y + o2.x * c01 + o2.y * c11 + o2.z * c21;
        float w2z = pj2.z - pi1.z + o2.x * c02 + o2.y * c12 + o2.z * c22;
        d = sqrtf(w2x * w2x + w2y * w2y + w2z * w2z + 1e-12f);
        float c2v = 0.f;
        if (m2 != 0.f && d < 6.f)
            c2v = 0.5f * (__cosf(d * 0.52359877559829887f) + 1.f) / d;
        w2x *= c2v; w2y *= c2v; w2z *= c2v;

        // ---- row0: rank + register merge ----
        // rank(m) = #{k: cut_k > cut_m} + #{k<m: cut_k == cut_m}
        float4 a4 = make_float4(0.f, 0.f, 0.f, 0.f);
        float2 a2 = make_float2(0.f, 0.f);
        unsigned long long t = __ballot(c0v != 0.f);
        while (t) {                                  // item m = s (c0 owner)
            const int s = (int)__builtin_ctzll(t); t &= t - 1;
            const float c = __shfl(c0v, s);
            const int rank = __popcll(__ballot(c0v > c))
                           + __popcll(__ballot(c1v > c) & LOWM)
                           + __popcll(__ballot(c0v == c) & ((1ull << s) - 1ull));
            merge3(a4, a2, 3 * rank,
                   __shfl(w0x, s), __shfl(w0y, s), __shfl(w0z, s), lane);
        }
        t = __ballot(c1v != 0.f) & LOWM;
        while (t) {                                  // item m = 64+s (c1 low)
            const int s = (int)__builtin_ctzll(t); t &= t - 1;
            const float c = __shfl(c1v, s);
            const int rank = __popcll(__ballot(c0v > c))
                           + __popcll(__ballot(c1v > c) & LOWM)
                           + __popcll(__ballot(c0v == c))
                           + __popcll(__ballot(c1v == c) & LOWM & ((1ull << s) - 1ull));
            merge3(a4, a2, 3 * rank,
                   __shfl(w1x, s), __shfl(w1y, s), __shfl(w1z, s), lane);
        }
        float* row0 = out + (size_t)q0 * OUT_W;
        {
            f32x4_t av = {a4.x, a4.y, a4.z, a4.w};
            __builtin_nontemporal_store(av, (f32x4_t*)row0 + lane);
            f32x2_t a2v = {a2.x, a2.y};
            __builtin_nontemporal_store(a2v, (f32x2_t*)(row0 + 256) + lane);
        }

        // ---- row1: rank + register merge ----
        float4 b4 = make_float4(0.f, 0.f, 0.f, 0.f);
        float2 b2 = make_float2(0.f, 0.f);
        t = __ballot(c1v != 0.f) & HIGHM;
        while (t) {                                  // item m = s-32 (c1 high)
            const int s = (int)__builtin_ctzll(t); t &= t - 1;
            const float c = __shfl(c1v, s);
            const int rank = __popcll(__ballot(c1v > c) & HIGHM)
                           + __popcll(__ballot(c2v > c))
                           + __popcll(__ballot(c1v == c) & HIGHM & ((1ull << s) - 1ull));
            merge3(b4, b2, 3 * rank,
                   __shfl(w1x, s), __shfl(w1y, s), __shfl(w1z, s), lane);
        }
        t = __ballot(c2v != 0.f);
        while (t) {                                  // item m = 32+s (c2 owner)
            const int s = (int)__builtin_ctzll(t); t &= t - 1;
            const float c = __shfl(c2v, s);
            const int rank = __popcll(__ballot(c1v > c) & HIGHM)
                           + __popcll(__ballot(c2v > c))
                           + __popcll(__ballot(c1v == c) & HIGHM)
                           + __popcll(__ballot(c2v == c) & ((1ull << s) - 1ull));
            merge3(b4, b2, 3 * rank,
                   __shfl(w2x, s), __shfl(w2y, s), __shfl(w2z, s), lane);
        }
        float* row1 = out + (size_t)(q0 + 1) * OUT_W;
        {
            f32x4_t bv = {b4.x, b4.y, b4.z, b4.w};
            __builtin_nontemporal_store(bv, (f32x4_t*)row1 + lane);
            f32x2_t b2v = {b2.x, b2.y};
            __builtin_nontemporal_store(b2v, (f32x2_t*)(row1 + 256) + lane);
        }
    }
}

extern "C" void kernel_launch(void* const* d_in, const int* in_sizes, int n_in,
                              void* d_out, int out_size, void* d_ws, size_t ws_size,
                              hipStream_t stream) {
    const float* positions = (const float*)d_in[0];
    const float* cell      = (const float*)d_in[1];
    const float* offsets   = (const float*)d_in[2];
    const float* mask      = (const float*)d_in[3];
    const int*   neighbors = (const int*)d_in[4];
    float*       out       = (float*)d_out;

    const int BN = in_sizes[0] / 3;        // B*N = 32768
    const int B  = in_sizes[1] / 9;        // 8
    const int N  = BN / B;                 // 4096

    dim3 block(64 * WPB, 1, 1);                // 512 threads = 8 waves
    dim3 grid(BN / (WPB * 2 * ITERS), 1, 1);   // 512 blocks = 2/CU resident
    deepmd_angular_kernel<<<grid, block, 0, stream>>>(
        positions, cell, offsets, mask, neighbors, out, N);
}

// Round 9
// 116.834 us; speedup vs baseline: 2.7516x; 1.0441x over previous
//
#include <hip/hip_runtime.h>
#include <math.h>

// Deepmd angular descriptor, f32 in / f32 out. B=8, N=4096, M=96, OUT_W=384.
//
// R24 = FINAL REVERT to R20 (best measured: 115.9 us; ties R15/R16 within
// noise). Session conclusion — kernel is at the environmental memory
// roofline:
//   compulsory traffic 113 MB (63 read + 50 write, counters confirm no
//   over-fetch) + ~113 MB dirty-victim writeback tax (harness poison fill
//   leaves the 256 MB L3 100% dirty before every timed iteration) =
//   ~226 MB actual HBM traffic @ ~6.6 TB/s = 34 us = observed kernel time.
// Falsified by direct measurement: occupancy 16<->32 w/CU (R15==R16), VGPR
// budget + depth-1..4 prefetch (R16/R22), global_load_lds + counted vmcnt
// (R18: -6us), zero-sync drift (R19: -10us), bytes/instr 427->768 (R20: =),
// nt cache bypass safe+aggressive (R22/R23: -6us). R21 spin-padded
// decomposition: cold loads alone 23 us, ballot/merge 11 us VALU (hides in
// saturated memory time). dur_us floor = 2 poison fills (~82 us, harness) +
// 34 us kernel ~= 116 us.
#define M_NB   96
#define OUT_W  384
#define NATOM  4096
#define WPB    8                    // waves per block (512 threads)
#define ITERS  4                    // 2 rows per iteration -> 8 rows/wave
#define LOWM   0x00000000FFFFFFFFull
#define HIGHM  0xFFFFFFFF00000000ull

// fold one item (row floats [base,base+3)) into this lane's output slots:
// float4 owns [4*lane,4*lane+4), float2 owns [256+2*lane,256+2*lane+2)
__device__ __forceinline__ void merge3(float4& a4, float2& a2, int base,
                                       float v0, float v1, float v2, int lane)
{
    const int f4lo = 4 * lane;
    const int f2lo = 256 + 2 * lane;
    const float v[3] = {v0, v1, v2};
    #pragma unroll
    for (int t = 0; t < 3; ++t) {
        const int idx = base + t;
        if      (idx == f4lo)     a4.x = v[t];
        else if (idx == f4lo + 1) a4.y = v[t];
        else if (idx == f4lo + 2) a4.z = v[t];
        else if (idx == f4lo + 3) a4.w = v[t];
        else if (idx == f2lo)     a2.x = v[t];
        else if (idx == f2lo + 1) a2.y = v[t];
    }
}

__global__ __launch_bounds__(64 * WPB, 4) void deepmd_angular_kernel(
    const float* __restrict__ positions,  // [B,N,3]
    const float* __restrict__ cell,       // [B,3,3]
    const float* __restrict__ offsets,    // [B,N,M,3]
    const float* __restrict__ mask,       // [B,N,M]
    const int*   __restrict__ neighbors,  // [B,N,M]
    float*       __restrict__ out,        // [B,N,OUT_W]
    int N)
{
    __shared__ float4 pos4_s[NATOM];        // 64 KB padded position table

    const int tid  = threadIdx.x;
    const int wv   = tid >> 6;
    const int lane = tid & 63;

    const int p0 = blockIdx.x * (WPB * 2 * ITERS);   // 64 rows per block
    const int b  = p0 / N;                           // uniform (64 | N)

    // ---- stage batch positions -> LDS (padded to 16 B/atom) ----
    {
        const float* pb_ = positions + (size_t)b * N * 3;
        for (int a = tid; a < NATOM; a += 64 * WPB) {
            const float3 v = *(const float3*)(pb_ + 3 * a);
            pos4_s[a] = make_float4(v.x, v.y, v.z, 0.f);
        }
    }
    __syncthreads();                             // only barrier in the kernel

    const float* cb = cell + (size_t)b * 9;      // uniform -> scalar loads
    const float c00 = cb[0], c01 = cb[1], c02 = cb[2];
    const float c10 = cb[3], c11 = cb[4], c12 = cb[5];
    const float c20 = cb[6], c21 = cb[7], c22 = cb[8];

    const int r0 = p0 + wv * (2 * ITERS);        // wave's first row
    const int lq = lane >> 2;                    // fat-load source sublane
    const int lc = lane & 3;                     // fat-load component select

    #pragma unroll
    for (int it = 0; it < ITERS; ++it) {
        const int  q0   = r0 + it * 2;           // first of this iter's 2 rows
        const long base = (long)q0 * M_NB;       // contiguous 192 elements

        // ---- fat stream loads: 768 B/instr ----
        int4   nv = make_int4(0, 0, 0, 0);
        float4 mv = make_float4(0.f, 0.f, 0.f, 0.f);
        if (lane < 48) {                         // 192 elems = 48 int4/float4
            nv = ((const int4*)  (neighbors + base))[lane];
            mv = ((const float4*)(mask      + base))[lane];
        }
        const float3 o0 = *(const float3*)(offsets + (base + lane) * 3);
        const float3 o1 = *(const float3*)(offsets + (base + lane + 64) * 3);
        const float3 o2 = *(const float3*)(offsets + (base + lane + 128) * 3);

        // ---- redistribute to R15 layout: slot s of lane l = component
        // (l&3) of fat-load lane 16*s+(l>>2) ----
        int   j0, j1, j2;
        float m0, m1, m2;
        #pragma unroll
        for (int s = 0; s < 3; ++s) {
            const int src = 16 * s + lq;
            const int   ax = __shfl(nv.x, src), ay = __shfl(nv.y, src);
            const int   az = __shfl(nv.z, src), aw = __shfl(nv.w, src);
            const int   jl = (lc & 1) ? ay : ax;
            const int   jh = (lc & 1) ? aw : az;
            const int   jj = (lc & 2) ? jh : jl;
            const float bx = __shfl(mv.x, src), by = __shfl(mv.y, src);
            const float bz = __shfl(mv.z, src), bw = __shfl(mv.w, src);
            const float ml = (lc & 1) ? by : bx;
            const float mh = (lc & 1) ? bw : bz;
            const float mm = (lc & 2) ? mh : ml;
            if (s == 0) { j0 = jj; m0 = mm; }
            else if (s == 1) { j1 = jj; m1 = mm; }
            else { j2 = jj; m2 = mm; }
        }

        // ---- LDS gathers ----
        const int nn0 = q0 - b * N;
        const float4 pi0 = pos4_s[nn0];          // uniform broadcasts
        const float4 pi1 = pos4_s[nn0 + 1];
        const float4 pj0 = pos4_s[j0];
        const float4 pj1 = pos4_s[j1];
        const float4 pj2 = pos4_s[j2];
        const float4 pa  = (lane < 32) ? pi0 : pi1;   // item1's own atom

        // ---- cut per item (w = cut * dis_vec stored in-place) ----
        float w0x = pj0.x - pi0.x + o0.x * c00 + o0.y * c10 + o0.z * c20;
        float w0y = pj0.y - pi0.y + o0.x * c01 + o0.y * c11 + o0.z * c21;
        float w0z = pj0.z - pi0.z + o0.x * c02 + o0.y * c12 + o0.z * c22;
        float d   = sqrtf(w0x * w0x + w0y * w0y + w0z * w0z + 1e-12f);
        float c0v = 0.f;
        if (m0 != 0.f && d < 6.f)
            c0v = 0.5f * (__cosf(d * 0.52359877559829887f) + 1.f) / d;
        w0x *= c0v; w0y *= c0v; w0z *= c0v;

        float w1x = pj1.x - pa.x + o1.x * c00 + o1.y * c10 + o1.z * c20;
        float w1y = pj1.y - pa.y + o1.x * c01 + o1.y * c11 + o1.z * c21;
        float w1z = pj1.z - pa.z + o1.x * c02 + o1.y * c12 + o1.z * c22;
        d = sqrtf(w1x * w1x + w1y * w1y + w1z * w1z + 1e-12f);
        float c1v = 0.f;
        if (m1 != 0.f && d < 6.f)
            c1v = 0.5f * (__cosf(d * 0.52359877559829887f) + 1.f) / d;
        w1x *= c1v; w1y *= c1v; w1z *= c1v;

        float w2x = pj2.x - pi1.x + o2.x * c00 + o2.y * c10 + o2.z * c20;
        float w2y = pj2.y - pi1.y + o2.x * c01 + o2.y * c11 + o2.z * c21;
        float w2z = pj2.z - pi1.z + o2.x * c02 + o2.y * c12 + o2.z * c22;
        d = sqrtf(w2x * w2x + w2y * w2y + w2z * w2z + 1e-12f);
        float c2v = 0.f;
        if (m2 != 0.f && d < 6.f)
            c2v = 0.5f * (__cosf(d * 0.52359877559829887f) + 1.f) / d;
        w2x *= c2v; w2y *= c2v; w2z *= c2v;

        // ---- row0: rank + register merge ----
        // rank(m) = #{k: cut_k > cut_m} + #{k<m: cut_k == cut_m}
        float4 a4 = make_float4(0.f, 0.f, 0.f, 0.f);
        float2 a2 = make_float2(0.f, 0.f);
        unsigned long long t = __ballot(c0v != 0.f);
        while (t) {                                  // item m = s (c0 owner)
            const int s = (int)__builtin_ctzll(t); t &= t - 1;
            const float c = __shfl(c0v, s);
            const int rank = __popcll(__ballot(c0v > c))
                           + __popcll(__ballot(c1v > c) & LOWM)
                           + __popcll(__ballot(c0v == c) & ((1ull << s) - 1ull));
            merge3(a4, a2, 3 * rank,
                   __shfl(w0x, s), __shfl(w0y, s), __shfl(w0z, s), lane);
        }
        t = __ballot(c1v != 0.f) & LOWM;
        while (t) {                                  // item m = 64+s (c1 low)
            const int s = (int)__builtin_ctzll(t); t &= t - 1;
            const float c = __shfl(c1v, s);
            const int rank = __popcll(__ballot(c0v > c))
                           + __popcll(__ballot(c1v > c) & LOWM)
                           + __popcll(__ballot(c0v == c))
                           + __popcll(__ballot(c1v == c) & LOWM & ((1ull << s) - 1ull));
            merge3(a4, a2, 3 * rank,
                   __shfl(w1x, s), __shfl(w1y, s), __shfl(w1z, s), lane);
        }
        float* row0 = out + (size_t)q0 * OUT_W;
        ((float4*)row0)[lane] = a4;
        ((float2*)(row0 + 256))[lane] = a2;

        // ---- row1: rank + register merge ----
        float4 b4 = make_float4(0.f, 0.f, 0.f, 0.f);
        float2 b2 = make_float2(0.f, 0.f);
        t = __ballot(c1v != 0.f) & HIGHM;
        while (t) {                                  // item m = s-32 (c1 high)
            const int s = (int)__builtin_ctzll(t); t &= t - 1;
            const float c = __shfl(c1v, s);
            const int rank = __popcll(__ballot(c1v > c) & HIGHM)
                           + __popcll(__ballot(c2v > c))
                           + __popcll(__ballot(c1v == c) & HIGHM & ((1ull << s) - 1ull));
            merge3(b4, b2, 3 * rank,
                   __shfl(w1x, s), __shfl(w1y, s), __shfl(w1z, s), lane);
        }
        t = __ballot(c2v != 0.f);
        while (t) {                                  // item m = 32+s (c2 owner)
            const int s = (int)__builtin_ctzll(t); t &= t - 1;
            const float c = __shfl(c2v, s);
            const int rank = __popcll(__ballot(c1v > c) & HIGHM)
                           + __popcll(__ballot(c2v > c))
                           + __popcll(__ballot(c1v == c) & HIGHM)
                           + __popcll(__ballot(c2v == c) & ((1ull << s) - 1ull));
            merge3(b4, b2, 3 * rank,
                   __shfl(w2x, s), __shfl(w2y, s), __shfl(w2z, s), lane);
        }
        float* row1 = out + (size_t)(q0 + 1) * OUT_W;
        ((float4*)row1)[lane] = b4;
        ((float2*)(row1 + 256))[lane] = b2;
    }
}

extern "C" void kernel_launch(void* const* d_in, const int* in_sizes, int n_in,
                              void* d_out, int out_size, void* d_ws, size_t ws_size,
                              hipStream_t stream) {
    const float* positions = (const float*)d_in[0];
    const float* cell      = (const float*)d_in[1];
    const float* offsets   = (const float*)d_in[2];
    const float* mask      = (const float*)d_in[3];
    const int*   neighbors = (const int*)d_in[4];
    float*       out       = (float*)d_out;

    const int BN = in_sizes[0] / 3;        // B*N = 32768
    const int B  = in_sizes[1] / 9;        // 8
    const int N  = BN / B;                 // 4096

    dim3 block(64 * WPB, 1, 1);                // 512 threads = 8 waves
    dim3 grid(BN / (WPB * 2 * ITERS), 1, 1);   // 512 blocks = 2/CU resident
    deepmd_angular_kernel<<<grid, block, 0, stream>>>(
        positions, cell, offsets, mask, neighbors, out, N);
}